// Round 10
// baseline (301.596 us; speedup 1.0000x reference)
//
#include <hip/hip_runtime.h>
#include <hip/hip_bf16.h>
#include <math.h>

#define N_NODES 50000
#define N_EDGESX 800000
#define E_TOT   (N_EDGESX + N_NODES)
#define IN_C 128
#define HID_C 256
#define OUT_C 128
#define NEG_SLOPE 0.2f

// bucketed counting sort params
#define NPB   100                         // nodes per bucket
#define NBUCK ((N_NODES + NPB - 1) / NPB) // 500
#define BCAP  2560                        // max edges per bucket (mean ~1700)
#define EPB   4096                        // edges per binA block
#define NABLK ((E_TOT + EPB - 1) / EPB)   // 208

typedef __attribute__((ext_vector_type(8))) short short8;
typedef __attribute__((ext_vector_type(4))) float floatx4;
typedef __attribute__((ext_vector_type(2))) float floatx2;

__device__ __forceinline__ float bf2f(short s) {
    unsigned u = ((unsigned)(unsigned short)s) << 16;
    float f; __builtin_memcpy(&f, &u, 4); return f;
}
__device__ __forceinline__ short f2bf(float f) {   // RNE
    unsigned u; __builtin_memcpy(&u, &f, 4);
    unsigned r = (u + 0x7FFFu + ((u >> 16) & 1u)) >> 16;
    return (short)r;
}

// ---------------- projected attention vectors: p[k] = sum_n W[k][n]*a[n] ----------------
template<int KROWS, int NCOLS>
__global__ __launch_bounds__(256)
void gemv_p_kernel(const float* __restrict__ W, const float* __restrict__ a_s,
                   const float* __restrict__ a_d, float* __restrict__ ps, float* __restrict__ pd) {
    int t = threadIdx.x;
    int k = t & (KROWS - 1);
    const float* av = (t < KROWS) ? a_s : a_d;
    float* pv = (t < KROWS) ? ps : pd;
    const float* row = W + (size_t)k * NCOLS;
    float s = 0.f;
    for (int n = 0; n < NCOLS; ++n) s += row[n] * av[n];
    pv[k] = s;
}

// ---------------- alpha1 from x + x->bf16 split (fused, one x pass) ----------------
__global__ __launch_bounds__(256)
void alpha_x_kernel(const float* __restrict__ x, const float* __restrict__ ps,
                    const float* __restrict__ pd, float* __restrict__ as_out,
                    float* __restrict__ ad_out, short* __restrict__ xb) {
    int gt = blockIdx.x * blockDim.x + threadIdx.x;
    int node = gt >> 6, lane = gt & 63;
    if (node >= N_NODES) return;
    floatx2 xv = *(const floatx2*)&x[(size_t)node * IN_C + lane * 2];
    floatx2 s2 = *(const floatx2*)&ps[lane * 2];
    floatx2 d2 = *(const floatx2*)&pd[lane * 2];
    float s = xv[0] * s2[0] + xv[1] * s2[1];
    float d = xv[0] * d2[0] + xv[1] * d2[1];
    unsigned pack = (unsigned)(unsigned short)f2bf(xv[0]) | ((unsigned)(unsigned short)f2bf(xv[1]) << 16);
    *(unsigned*)&xb[(size_t)node * IN_C + lane * 2] = pack;
    #pragma unroll
    for (int off = 32; off; off >>= 1) {
        s += __shfl_down(s, off);
        d += __shfl_down(d, off);
    }
    if (lane == 0) { as_out[node] = s; ad_out[node] = d; }
}

// ---------------- C = max(a) + max(b), single block ----------------
__global__ __launch_bounds__(1024)
void maxred_kernel(const float* __restrict__ a, const float* __restrict__ b,
                   float* __restrict__ c) {
    __shared__ float sa[16], sb[16];
    int t = threadIdx.x;
    float ma = -1e30f, mb = -1e30f;
    for (int i = t; i < N_NODES; i += 1024) {
        ma = fmaxf(ma, a[i]);
        mb = fmaxf(mb, b[i]);
    }
    #pragma unroll
    for (int off = 32; off; off >>= 1) {
        ma = fmaxf(ma, __shfl_down(ma, off));
        mb = fmaxf(mb, __shfl_down(mb, off));
    }
    if ((t & 63) == 0) { sa[t >> 6] = ma; sb[t >> 6] = mb; }
    __syncthreads();
    if (t < 16) {
        ma = sa[t]; mb = sb[t];
        #pragma unroll
        for (int off = 8; off; off >>= 1) {
            ma = fmaxf(ma, __shfl_down(ma, off));
            mb = fmaxf(mb, __shfl_down(mb, off));
        }
        if (t == 0) c[0] = ma + mb;
    }
}

// ---------------- bucketed CSR build ----------------
// stage entry: packed (li<<17 | s), li = d % NPB (<128), s < 2^17
__global__ __launch_bounds__(256)
void binA_kernel(const int* __restrict__ src, const int* __restrict__ dst,
                 int* __restrict__ bcnt, int* __restrict__ stage) {
    __shared__ int hist[NBUCK];
    __shared__ int base[NBUCK];
    for (int b = threadIdx.x; b < NBUCK; b += 256) hist[b] = 0;
    __syncthreads();
    int e0 = blockIdx.x * EPB;
    int e1 = min(e0 + EPB, E_TOT);
    for (int i = e0 + threadIdx.x; i < e1; i += 256) {
        int d = (i < N_EDGESX) ? dst[i] : (i - N_EDGESX);
        atomicAdd(&hist[d / NPB], 1);
    }
    __syncthreads();
    for (int b = threadIdx.x; b < NBUCK; b += 256) {
        int c = hist[b];
        base[b] = c ? atomicAdd(&bcnt[b], c) : 0;
        hist[b] = 0;
    }
    __syncthreads();
    for (int i = e0 + threadIdx.x; i < e1; i += 256) {
        int s, d;
        if (i < N_EDGESX) { s = src[i]; d = dst[i]; }
        else { s = i - N_EDGESX; d = s; }
        int b = d / NPB;
        int off = base[b] + atomicAdd(&hist[b], 1);
        if (off < BCAP) stage[(size_t)b * BCAP + off] = ((d - b * NPB) << 17) | s;
    }
}

// B: per-bucket per-node counts (LDS), coalesced cnt writes
__global__ __launch_bounds__(128)
void bucket_count_kernel(const int* __restrict__ bcnt, const int* __restrict__ stage,
                         int* __restrict__ cnt) {
    __shared__ int lc[NPB];
    int b = blockIdx.x;
    for (int t = threadIdx.x; t < NPB; t += 128) lc[t] = 0;
    __syncthreads();
    int n = min(bcnt[b], BCAP);
    const int* sp = stage + (size_t)b * BCAP;
    for (int i = threadIdx.x; i < n; i += 128)
        atomicAdd(&lc[sp[i] >> 17], 1);
    __syncthreads();
    int nb = b * NPB;
    for (int t = threadIdx.x; t < NPB; t += 128)
        if (nb + t < N_NODES) cnt[nb + t] = lc[t];
}

// C: scatter esrc via LDS cursors + fused layer-1 edge weights we = exp(lrelu(e) - C)
__global__ __launch_bounds__(128)
void bucket_scatter_kernel(const int* __restrict__ bcnt, const int* __restrict__ stage,
                           const int* __restrict__ row_ptr, const float* __restrict__ as_in,
                           const float* __restrict__ ad_in, const float* __restrict__ Cptr,
                           int* __restrict__ esrc, float* __restrict__ we) {
    __shared__ int cur[NPB];
    __shared__ float adl[NPB];
    int b = blockIdx.x;
    int nb = b * NPB;
    float C = Cptr[0];
    for (int t = threadIdx.x; t < NPB; t += 128) {
        int node = nb + t;
        cur[t] = (node < N_NODES) ? row_ptr[node] : 0;
        adl[t] = (node < N_NODES) ? ad_in[node] : 0.f;
    }
    __syncthreads();
    int n = min(bcnt[b], BCAP);
    const int* sp = stage + (size_t)b * BCAP;
    for (int i = threadIdx.x; i < n; i += 128) {
        int v = sp[i];
        int s = v & 0x1FFFF;
        int li = v >> 17;
        int pos = atomicAdd(&cur[li], 1);
        esrc[pos] = s;
        float e = as_in[s] + adl[li];
        e = fmaxf(e, NEG_SLOPE * e);   // leakyrelu
        we[pos] = __expf(e - C);
    }
}

#define NBLK ((N_NODES + 1023) / 1024)   // 49

__global__ __launch_bounds__(1024)
void scan_a_kernel(const int* __restrict__ cnt, int* __restrict__ row_ptr, int* __restrict__ bsum) {
    __shared__ int buf[1024];
    int tid = threadIdx.x;
    int idx = blockIdx.x * 1024 + tid;
    int v = (idx < N_NODES) ? cnt[idx] : 0;
    buf[tid] = v;
    __syncthreads();
    for (int off = 1; off < 1024; off <<= 1) {
        int t = (tid >= off) ? buf[tid - off] : 0;
        __syncthreads();
        buf[tid] += t;
        __syncthreads();
    }
    if (idx < N_NODES) row_ptr[idx] = buf[tid] - v;
    if (tid == 1023) bsum[blockIdx.x] = buf[1023];
}

__global__ void scan_b_kernel(int* __restrict__ bsum, int* __restrict__ row_ptr) {
    int lane = threadIdx.x;   // 64
    int v = (lane < NBLK) ? bsum[lane] : 0;
    int s = v;
    #pragma unroll
    for (int off = 1; off < 64; off <<= 1) {
        int t = __shfl_up(s, off);
        if (lane >= off) s += t;
    }
    if (lane < NBLK) bsum[lane] = s - v;
    if (lane == 63) row_ptr[N_NODES] = s;
}

__global__ __launch_bounds__(1024)
void scan_c_kernel(int* __restrict__ row_ptr, const int* __restrict__ bsum) {
    int idx = blockIdx.x * 1024 + threadIdx.x;
    if (idx < N_NODES) row_ptr[idx] += bsum[blockIdx.x];
}

// ---------------- W[K][N] -> Wt hi/lo [N][K] ----------------
__global__ void splitT_kernel(const float* __restrict__ W, short* __restrict__ th,
                              short* __restrict__ tl, int K, int N) {
    int i = blockIdx.x * blockDim.x + threadIdx.x;
    if (i >= K * N) return;
    int k = i / N, n = i - k * N;
    float f = W[i];
    short hb = f2bf(f);
    th[n * K + k] = hb;
    tl[n * K + k] = f2bf(f - bf2f(hb));
}

// ---------------- split-bf16 MFMA GEMM ----------------
// C = A[M,K] @ (Bh+Bl)[K,N], Bt stored [N][K]. BM=128, BN=64, 4 waves, 2 MFMA passes.
// OUTMODE 1: plain bf16 -> C0.  OUTMODE 2: relu(v+bias[gc]) -> bf16 C0.
template<int K, int OUTMODE>
__global__ __launch_bounds__(256)
void gemm_mfma(const short* __restrict__ Ah,
               const short* __restrict__ Bth, const short* __restrict__ Btl,
               int N, const float* __restrict__ bias, short* __restrict__ C0) {
    __shared__ short Ah_s[128][40];
    __shared__ short Bh_s[64][40];
    __shared__ short Bl_s[64][40];
    int tid = threadIdx.x;
    int lane = tid & 63, wave = tid >> 6;
    int wr = wave >> 1, wc = wave & 1;
    int bm = blockIdx.y * 128, bn = blockIdx.x * 64;
    int l15 = lane & 15, kf = (lane >> 4) * 8;

    floatx4 acc[4][2];
    #pragma unroll
    for (int i = 0; i < 4; ++i)
        #pragma unroll
        for (int j = 0; j < 2; ++j) acc[i][j] = (floatx4){0.f, 0.f, 0.f, 0.f};

    int arow = tid >> 1, ac0 = (tid & 1) * 16;
    int brow = tid >> 2, bc0 = (tid & 3) * 8;
    int agm = bm + arow;
    bool aval = agm < N_NODES;

    for (int k0 = 0; k0 < K; k0 += 32) {
        short8 va0 = {0,0,0,0,0,0,0,0}, va1 = va0;
        if (aval) {
            const short* pa = Ah + (size_t)agm * K + k0 + ac0;
            va0 = *(const short8*)pa; va1 = *(const short8*)(pa + 8);
        }
        *(short8*)&Ah_s[arow][ac0]     = va0;
        *(short8*)&Ah_s[arow][ac0 + 8] = va1;
        {
            const short* pb = Bth + (size_t)(bn + brow) * K + k0 + bc0;
            *(short8*)&Bh_s[brow][bc0] = *(const short8*)pb;
            const short* pb2 = Btl + (size_t)(bn + brow) * K + k0 + bc0;
            *(short8*)&Bl_s[brow][bc0] = *(const short8*)pb2;
        }
        __syncthreads();
        short8 afh[4], bfh[2], bfl[2];
        #pragma unroll
        for (int mr = 0; mr < 4; ++mr) {
            int r = wr * 64 + mr * 16 + l15;
            afh[mr] = *(const short8*)&Ah_s[r][kf];
        }
        #pragma unroll
        for (int nr = 0; nr < 2; ++nr) {
            int c = wc * 32 + nr * 16 + l15;
            bfh[nr] = *(const short8*)&Bh_s[c][kf];
            bfl[nr] = *(const short8*)&Bl_s[c][kf];
        }
        #pragma unroll
        for (int mr = 0; mr < 4; ++mr)
            #pragma unroll
            for (int nr = 0; nr < 2; ++nr) {
                acc[mr][nr] = __builtin_amdgcn_mfma_f32_16x16x32_bf16(afh[mr], bfh[nr], acc[mr][nr], 0, 0, 0);
                acc[mr][nr] = __builtin_amdgcn_mfma_f32_16x16x32_bf16(afh[mr], bfl[nr], acc[mr][nr], 0, 0, 0);
            }
        __syncthreads();
    }
    float bv[2];
    if (OUTMODE == 2) {
        #pragma unroll
        for (int nr = 0; nr < 2; ++nr) bv[nr] = bias[bn + wc * 32 + nr * 16 + l15];
    }
    #pragma unroll
    for (int mr = 0; mr < 4; ++mr) {
        #pragma unroll
        for (int reg = 0; reg < 4; ++reg) {
            int gr = bm + wr * 64 + mr * 16 + (lane >> 4) * 4 + reg;
            if (gr < N_NODES) {
                #pragma unroll
                for (int nr = 0; nr < 2; ++nr) {
                    int gc = bn + wc * 32 + nr * 16 + l15;
                    float v = acc[mr][nr][reg];
                    if (OUTMODE == 2) v = fmaxf(v + bv[nr], 0.f);
                    C0[(size_t)gr * N + gc] = f2bf(v);
                }
            }
        }
    }
}

// ---------------- alpha2 from h2 (bf16) ----------------
__global__ __launch_bounds__(256)
void alpha_bf16_128(const short* __restrict__ h, const float* __restrict__ a_src,
                    const float* __restrict__ a_dst, float* __restrict__ as_out,
                    float* __restrict__ ad_out) {
    int gt = blockIdx.x * blockDim.x + threadIdx.x;
    int node = gt >> 6, lane = gt & 63;
    if (node >= N_NODES) return;
    unsigned u = *(const unsigned*)&h[(size_t)node * OUT_C + lane * 2];
    float v0 = bf2f((short)(u & 0xFFFFu));
    float v1 = bf2f((short)(u >> 16));
    floatx2 as2 = *(const floatx2*)&a_src[lane * 2];
    floatx2 ad2 = *(const floatx2*)&a_dst[lane * 2];
    float s = v0 * as2[0] + v1 * as2[1];
    float d = v0 * ad2[0] + v1 * ad2[1];
    #pragma unroll
    for (int off = 32; off; off >>= 1) {
        s += __shfl_down(s, off);
        d += __shfl_down(d, off);
    }
    if (lane == 0) { as_out[node] = s; ad_out[node] = d; }
}

// ---------------- layer-1 aggregate: single pass, precomputed we, bf16 u out ----------------
__global__ __launch_bounds__(256)
void aggregate1_kernel(const short* __restrict__ h, const float* __restrict__ we,
                       const int* __restrict__ row_ptr, const int* __restrict__ esrc,
                       short* __restrict__ o_u) {
    int gt = blockIdx.x * blockDim.x + threadIdx.x;
    int node = gt >> 6, lane = gt & 63;
    if (node >= N_NODES) return;
    int beg = row_ptr[node], end = row_ptr[node + 1];
    int grp = lane >> 4, l = lane & 15;
    float acc[8] = {};
    float zl = 0.f;
    int i = beg;
    for (; i + 16 <= end; i += 16) {
        int e0 = i + grp, e1 = e0 + 4, e2 = e0 + 8, e3 = e0 + 12;
        int s0 = esrc[e0], s1 = esrc[e1], s2 = esrc[e2], s3 = esrc[e3];
        float w0 = we[e0], w1 = we[e1], w2 = we[e2], w3 = we[e3];
        short8 hv0 = *(const short8*)&h[(size_t)s0 * 128 + l * 8];
        short8 hv1 = *(const short8*)&h[(size_t)s1 * 128 + l * 8];
        short8 hv2 = *(const short8*)&h[(size_t)s2 * 128 + l * 8];
        short8 hv3 = *(const short8*)&h[(size_t)s3 * 128 + l * 8];
        zl += (w0 + w1) + (w2 + w3);
        #pragma unroll
        for (int j = 0; j < 8; ++j) acc[j] += w0 * bf2f(hv0[j]);
        #pragma unroll
        for (int j = 0; j < 8; ++j) acc[j] += w1 * bf2f(hv1[j]);
        #pragma unroll
        for (int j = 0; j < 8; ++j) acc[j] += w2 * bf2f(hv2[j]);
        #pragma unroll
        for (int j = 0; j < 8; ++j) acc[j] += w3 * bf2f(hv3[j]);
    }
    for (; i < end; i += 4) {
        int e = i + grp;
        bool v = e < end;
        int s = esrc[v ? e : beg];
        float w = v ? we[e] : 0.f;
        short8 hv = *(const short8*)&h[(size_t)s * 128 + l * 8];
        zl += w;
        #pragma unroll
        for (int j = 0; j < 8; ++j) acc[j] += w * bf2f(hv[j]);
    }
    zl += __shfl_xor(zl, 16);
    zl += __shfl_xor(zl, 32);
    #pragma unroll
    for (int j = 0; j < 8; ++j) {
        acc[j] += __shfl_xor(acc[j], 16);
        acc[j] += __shfl_xor(acc[j], 32);
    }
    float invz = 1.f / zl;
    if (lane < 16) {
        short8 oh;
        #pragma unroll
        for (int j = 0; j < 8; ++j) oh[j] = f2bf(acc[j] * invz);
        *(short8*)&o_u[(size_t)node * 128 + l * 8] = oh;
    }
}

// ---------------- layer-2 aggregate: single pass, inline we from as2/ad2, fp32 out ----------------
__global__ __launch_bounds__(256)
void aggregate2_kernel(const short* __restrict__ h, const float* __restrict__ as2,
                       const float* __restrict__ ad2, const float* __restrict__ Cptr,
                       const int* __restrict__ row_ptr, const int* __restrict__ esrc,
                       const float* __restrict__ bias, float* __restrict__ out) {
    int gt = blockIdx.x * blockDim.x + threadIdx.x;
    int node = gt >> 6, lane = gt & 63;
    if (node >= N_NODES) return;
    int beg = row_ptr[node], end = row_ptr[node + 1];
    float C = Cptr[0];
    float adn = ad2[node];
    int grp = lane >> 4, l = lane & 15;
    float acc[8] = {};
    float zl = 0.f;
    int i = beg;
    for (; i + 16 <= end; i += 16) {
        int e0 = i + grp, e1 = e0 + 4, e2 = e0 + 8, e3 = e0 + 12;
        int s0 = esrc[e0], s1 = esrc[e1], s2 = esrc[e2], s3 = esrc[e3];
        float t0 = as2[s0] + adn, t1 = as2[s1] + adn, t2 = as2[s2] + adn, t3 = as2[s3] + adn;
        t0 = fmaxf(t0, NEG_SLOPE * t0); t1 = fmaxf(t1, NEG_SLOPE * t1);
        t2 = fmaxf(t2, NEG_SLOPE * t2); t3 = fmaxf(t3, NEG_SLOPE * t3);
        float w0 = __expf(t0 - C), w1 = __expf(t1 - C);
        float w2 = __expf(t2 - C), w3 = __expf(t3 - C);
        short8 hv0 = *(const short8*)&h[(size_t)s0 * 128 + l * 8];
        short8 hv1 = *(const short8*)&h[(size_t)s1 * 128 + l * 8];
        short8 hv2 = *(const short8*)&h[(size_t)s2 * 128 + l * 8];
        short8 hv3 = *(const short8*)&h[(size_t)s3 * 128 + l * 8];
        zl += (w0 + w1) + (w2 + w3);
        #pragma unroll
        for (int j = 0; j < 8; ++j) acc[j] += w0 * bf2f(hv0[j]);
        #pragma unroll
        for (int j = 0; j < 8; ++j) acc[j] += w1 * bf2f(hv1[j]);
        #pragma unroll
        for (int j = 0; j < 8; ++j) acc[j] += w2 * bf2f(hv2[j]);
        #pragma unroll
        for (int j = 0; j < 8; ++j) acc[j] += w3 * bf2f(hv3[j]);
    }
    for (; i < end; i += 4) {
        int e = i + grp;
        bool v = e < end;
        int s = esrc[v ? e : beg];
        float t = as2[s] + adn;
        t = fmaxf(t, NEG_SLOPE * t);
        float w = v ? __expf(t - C) : 0.f;
        short8 hv = *(const short8*)&h[(size_t)s * 128 + l * 8];
        zl += w;
        #pragma unroll
        for (int j = 0; j < 8; ++j) acc[j] += w * bf2f(hv[j]);
    }
    zl += __shfl_xor(zl, 16);
    zl += __shfl_xor(zl, 32);
    #pragma unroll
    for (int j = 0; j < 8; ++j) {
        acc[j] += __shfl_xor(acc[j], 16);
        acc[j] += __shfl_xor(acc[j], 32);
    }
    float invz = 1.f / zl;
    if (lane < 16) {
        const float* brow = &bias[l * 8];
        floatx4 o0, o1;
        #pragma unroll
        for (int j = 0; j < 4; ++j) {
            o0[j] = acc[j] * invz + brow[j];
            o1[j] = acc[j + 4] * invz + brow[j + 4];
        }
        float* orow = &out[(size_t)node * 128 + l * 8];
        *(floatx4*)orow = o0;
        *(floatx4*)(orow + 4) = o1;
    }
}

// ---------------- launch ----------------
extern "C" void kernel_launch(void* const* d_in, const int* in_sizes, int n_in,
                              void* d_out, int out_size, void* d_ws, size_t ws_size,
                              hipStream_t stream) {
    const float* x   = (const float*)d_in[0];
    const int*   ei  = (const int*)d_in[1];
    const float* W1  = (const float*)d_in[2];
    const float* a1s = (const float*)d_in[3];
    const float* a1d = (const float*)d_in[4];
    const float* b1  = (const float*)d_in[5];
    const float* W2  = (const float*)d_in[6];
    const float* a2s = (const float*)d_in[7];
    const float* a2d = (const float*)d_in[8];
    const float* b2  = (const float*)d_in[9];
    float* out = (float*)d_out;

    const int* e_src = ei;
    const int* e_dst = ei + N_EDGESX;

    char* ws = (char*)d_ws;
    const size_t OFF_XB    = 0;             // bf16 [N][128]
    const size_t OFF_UH    = 12800000;      // bf16 [N][128]
    const size_t OFF_G1H   = 25600000;      // bf16 [N][256]
    const size_t OFF_H2    = 51200000;      // bf16 [N][128]
    const size_t OFF_W1TH  = 64000000;
    const size_t OFF_W1TL  = 64065536;
    const size_t OFF_W2TH  = 64131072;
    const size_t OFF_W2TL  = 64196608;
    const size_t OFF_P1S   = 64262144;
    const size_t OFF_P1D   = 64262656;
    const size_t OFF_CMAX  = 64263168;      // 2 floats
    const size_t OFF_AS    = 64263424;
    const size_t OFF_AD    = 64463616;
    const size_t OFF_RP    = 64663808;
    const size_t OFF_CNT   = 64864256;
    const size_t OFF_BSUM  = 65064448;
    const size_t OFF_BCNT  = 65064704;
    const size_t OFF_ESRC  = 65066752;      // E_TOT*4
    const size_t OFF_WE    = 68466752;      // E_TOT*4
    const size_t OFF_STAGE = 71866752;      // int [NBUCK][BCAP] = 5.12 MB

    short* xb   = (short*)(ws + OFF_XB);
    short* uh   = (short*)(ws + OFF_UH);
    short* g1h  = (short*)(ws + OFF_G1H);
    short* h2   = (short*)(ws + OFF_H2);
    short* w1th = (short*)(ws + OFF_W1TH);
    short* w1tl = (short*)(ws + OFF_W1TL);
    short* w2th = (short*)(ws + OFF_W2TH);
    short* w2tl = (short*)(ws + OFF_W2TL);
    float* p1s  = (float*)(ws + OFF_P1S);
    float* p1d  = (float*)(ws + OFF_P1D);
    float* cmax = (float*)(ws + OFF_CMAX);
    float* as_b = (float*)(ws + OFF_AS);
    float* ad_b = (float*)(ws + OFF_AD);
    int* row_ptr = (int*)(ws + OFF_RP);
    int* cnt     = (int*)(ws + OFF_CNT);
    int* bsum    = (int*)(ws + OFF_BSUM);
    int* bcnt    = (int*)(ws + OFF_BCNT);
    int* esrc    = (int*)(ws + OFF_ESRC);
    float* web   = (float*)(ws + OFF_WE);
    int* stage   = (int*)(ws + OFF_STAGE);

    int ngrid = (N_NODES * 64 + 255) / 256;

    // --- alpha1 (from x) + xb split + global offset C1 ---
    gemv_p_kernel<IN_C, HID_C><<<1, 256, 0, stream>>>(W1, a1s, a1d, p1s, p1d);
    alpha_x_kernel<<<ngrid, 256, 0, stream>>>(x, p1s, p1d, as_b, ad_b, xb);
    maxred_kernel<<<1, 1024, 0, stream>>>(as_b, ad_b, cmax);

    // --- bucketed CSR build (+ fused layer-1 weights) ---
    hipMemsetAsync(bcnt, 0, NBUCK * sizeof(int), stream);
    binA_kernel<<<NABLK, 256, 0, stream>>>(e_src, e_dst, bcnt, stage);
    bucket_count_kernel<<<NBUCK, 128, 0, stream>>>(bcnt, stage, cnt);
    scan_a_kernel<<<NBLK, 1024, 0, stream>>>(cnt, row_ptr, bsum);
    scan_b_kernel<<<1, 64, 0, stream>>>(bsum, row_ptr);
    scan_c_kernel<<<NBLK, 1024, 0, stream>>>(row_ptr, bsum);
    bucket_scatter_kernel<<<NBUCK, 128, 0, stream>>>(bcnt, stage, row_ptr, as_b, ad_b, cmax, esrc, web);

    // --- weight splits ---
    splitT_kernel<<<(IN_C * HID_C + 255) / 256, 256, 0, stream>>>(W1, w1th, w1tl, IN_C, HID_C);
    splitT_kernel<<<(HID_C * OUT_C + 255) / 256, 256, 0, stream>>>(W2, w2th, w2tl, HID_C, OUT_C);

    // --- layer 1: aggregate x (single pass), then transform (bias+relu fused) ---
    aggregate1_kernel<<<ngrid, 256, 0, stream>>>(xb, web, row_ptr, esrc, uh);
    gemm_mfma<IN_C, 2><<<dim3(HID_C / 64, (N_NODES + 127) / 128), 256, 0, stream>>>(
        uh, w1th, w1tl, HID_C, b1, g1h);

    // --- layer 2: transform, then aggregate (inline weights) ---
    gemm_mfma<HID_C, 1><<<dim3(OUT_C / 64, (N_NODES + 127) / 128), 256, 0, stream>>>(
        g1h, w2th, w2tl, OUT_C, nullptr, h2);
    alpha_bf16_128<<<ngrid, 256, 0, stream>>>(h2, a2s, a2d, as_b, ad_b);
    maxred_kernel<<<1, 1024, 0, stream>>>(as_b, ad_b, cmax + 1);
    aggregate2_kernel<<<ngrid, 256, 0, stream>>>(h2, as_b, ad_b, cmax + 1, row_ptr, esrc, b2, out);
}

// Round 11
// 292.830 us; speedup vs baseline: 1.0299x; 1.0299x over previous
//
#include <hip/hip_runtime.h>
#include <hip/hip_bf16.h>
#include <math.h>

#define N_NODES 50000
#define N_EDGESX 800000
#define E_TOT   (N_EDGESX + N_NODES)
#define IN_C 128
#define HID_C 256
#define OUT_C 128
#define NEG_SLOPE 0.2f

// bucketed counting sort params
#define NPB   100                         // nodes per bucket
#define NBUCK ((N_NODES + NPB - 1) / NPB) // 500
#define BCAP  2560                        // max edges per bucket (mean ~1700)
#define EPB   4096                        // edges per binA block
#define NABLK ((E_TOT + EPB - 1) / EPB)   // 208

typedef __attribute__((ext_vector_type(8))) short short8;
typedef __attribute__((ext_vector_type(4))) float floatx4;
typedef __attribute__((ext_vector_type(2))) float floatx2;

__device__ __forceinline__ float bf2f(short s) {
    unsigned u = ((unsigned)(unsigned short)s) << 16;
    float f; __builtin_memcpy(&f, &u, 4); return f;
}
__device__ __forceinline__ short f2bf(float f) {   // RNE
    unsigned u; __builtin_memcpy(&u, &f, 4);
    unsigned r = (u + 0x7FFFu + ((u >> 16) & 1u)) >> 16;
    return (short)r;
}

// ---------------- projected attention vectors: p[k] = sum_n W[k][n]*a[n] ----------------
template<int KROWS, int NCOLS>
__global__ __launch_bounds__(256)
void gemv_p_kernel(const float* __restrict__ W, const float* __restrict__ a_s,
                   const float* __restrict__ a_d, float* __restrict__ ps, float* __restrict__ pd) {
    int t = threadIdx.x;
    int k = t & (KROWS - 1);
    const float* av = (t < KROWS) ? a_s : a_d;
    float* pv = (t < KROWS) ? ps : pd;
    const float* row = W + (size_t)k * NCOLS;
    float s = 0.f;
    for (int n = 0; n < NCOLS; ++n) s += row[n] * av[n];
    pv[k] = s;
}

// ---------------- alpha1 from x + x->bf16 split (fused, one x pass) ----------------
__global__ __launch_bounds__(256)
void alpha_x_kernel(const float* __restrict__ x, const float* __restrict__ ps,
                    const float* __restrict__ pd, float* __restrict__ as_out,
                    float* __restrict__ ad_out, short* __restrict__ xb) {
    int gt = blockIdx.x * blockDim.x + threadIdx.x;
    int node = gt >> 6, lane = gt & 63;
    if (node >= N_NODES) return;
    floatx2 xv = *(const floatx2*)&x[(size_t)node * IN_C + lane * 2];
    floatx2 s2 = *(const floatx2*)&ps[lane * 2];
    floatx2 d2 = *(const floatx2*)&pd[lane * 2];
    float s = xv[0] * s2[0] + xv[1] * s2[1];
    float d = xv[0] * d2[0] + xv[1] * d2[1];
    unsigned pack = (unsigned)(unsigned short)f2bf(xv[0]) | ((unsigned)(unsigned short)f2bf(xv[1]) << 16);
    *(unsigned*)&xb[(size_t)node * IN_C + lane * 2] = pack;
    #pragma unroll
    for (int off = 32; off; off >>= 1) {
        s += __shfl_down(s, off);
        d += __shfl_down(d, off);
    }
    if (lane == 0) { as_out[node] = s; ad_out[node] = d; }
}

// ---------------- C = max(a) + max(b), single block ----------------
__global__ __launch_bounds__(1024)
void maxred_kernel(const float* __restrict__ a, const float* __restrict__ b,
                   float* __restrict__ c) {
    __shared__ float sa[16], sb[16];
    int t = threadIdx.x;
    float ma = -1e30f, mb = -1e30f;
    for (int i = t; i < N_NODES; i += 1024) {
        ma = fmaxf(ma, a[i]);
        mb = fmaxf(mb, b[i]);
    }
    #pragma unroll
    for (int off = 32; off; off >>= 1) {
        ma = fmaxf(ma, __shfl_down(ma, off));
        mb = fmaxf(mb, __shfl_down(mb, off));
    }
    if ((t & 63) == 0) { sa[t >> 6] = ma; sb[t >> 6] = mb; }
    __syncthreads();
    if (t < 16) {
        ma = sa[t]; mb = sb[t];
        #pragma unroll
        for (int off = 8; off; off >>= 1) {
            ma = fmaxf(ma, __shfl_down(ma, off));
            mb = fmaxf(mb, __shfl_down(mb, off));
        }
        if (t == 0) c[0] = ma + mb;
    }
}

// ---------------- bucketed CSR build ----------------
// stage entry: packed (li<<17 | s), li = d % NPB (<128), s < 2^17
__global__ __launch_bounds__(256)
void binA_kernel(const int* __restrict__ src, const int* __restrict__ dst,
                 int* __restrict__ bcnt, int* __restrict__ stage) {
    __shared__ int hist[NBUCK];
    __shared__ int base[NBUCK];
    for (int b = threadIdx.x; b < NBUCK; b += 256) hist[b] = 0;
    __syncthreads();
    int e0 = blockIdx.x * EPB;
    int e1 = min(e0 + EPB, E_TOT);
    for (int i = e0 + threadIdx.x; i < e1; i += 256) {
        int d = (i < N_EDGESX) ? dst[i] : (i - N_EDGESX);
        atomicAdd(&hist[d / NPB], 1);
    }
    __syncthreads();
    for (int b = threadIdx.x; b < NBUCK; b += 256) {
        int c = hist[b];
        base[b] = c ? atomicAdd(&bcnt[b], c) : 0;
        hist[b] = 0;
    }
    __syncthreads();
    for (int i = e0 + threadIdx.x; i < e1; i += 256) {
        int s, d;
        if (i < N_EDGESX) { s = src[i]; d = dst[i]; }
        else { s = i - N_EDGESX; d = s; }
        int b = d / NPB;
        int off = base[b] + atomicAdd(&hist[b], 1);
        if (off < BCAP) stage[(size_t)b * BCAP + off] = ((d - b * NPB) << 17) | s;
    }
}

// B: per-bucket per-node counts + local exclusive scan -> row_ptr (local), bsum[b] = total
__global__ __launch_bounds__(128)
void bucket_count_scan_kernel(const int* __restrict__ bcnt, const int* __restrict__ stage,
                              int* __restrict__ row_ptr, int* __restrict__ bsum) {
    __shared__ int lc[NPB];
    __shared__ int sc[128];
    int b = blockIdx.x, t = threadIdx.x;
    if (t < NPB) lc[t] = 0;
    __syncthreads();
    int n = min(bcnt[b], BCAP);
    const int* sp = stage + (size_t)b * BCAP;
    for (int i = t; i < n; i += 128) atomicAdd(&lc[sp[i] >> 17], 1);
    __syncthreads();
    int v = (t < NPB) ? lc[t] : 0;
    sc[t] = v;
    __syncthreads();
    #pragma unroll
    for (int off = 1; off < 128; off <<= 1) {
        int u = (t >= off) ? sc[t - off] : 0;
        __syncthreads();
        sc[t] += u;
        __syncthreads();
    }
    int nb = b * NPB;
    if (t < NPB && nb + t < N_NODES) row_ptr[nb + t] = sc[t] - v;   // local exclusive
    if (t == 127) bsum[b] = sc[127];
}

// single-block scan over NBUCK bucket totals -> exclusive bucket offsets (in-place)
__global__ __launch_bounds__(512)
void scan_bucket_kernel(int* __restrict__ bsum, int* __restrict__ row_ptr) {
    __shared__ int sc[512];
    int t = threadIdx.x;
    int v = (t < NBUCK) ? bsum[t] : 0;
    sc[t] = v;
    __syncthreads();
    #pragma unroll
    for (int off = 1; off < 512; off <<= 1) {
        int u = (t >= off) ? sc[t - off] : 0;
        __syncthreads();
        sc[t] += u;
        __syncthreads();
    }
    if (t < NBUCK) bsum[t] = sc[t] - v;     // exclusive offsets
    if (t == 511) row_ptr[N_NODES] = sc[511];
}

// row_ptr[idx] += bucket offset
__global__ __launch_bounds__(256)
void scan_add_kernel(int* __restrict__ row_ptr, const int* __restrict__ bsum) {
    int idx = blockIdx.x * 256 + threadIdx.x;
    if (idx < N_NODES) row_ptr[idx] += bsum[idx / NPB];
}

// C: scatter esrc via LDS cursors + fused layer-1 edge weights we = exp(lrelu(e) - C)
__global__ __launch_bounds__(128)
void bucket_scatter_kernel(const int* __restrict__ bcnt, const int* __restrict__ stage,
                           const int* __restrict__ row_ptr, const float* __restrict__ as_in,
                           const float* __restrict__ ad_in, const float* __restrict__ Cptr,
                           int* __restrict__ esrc, float* __restrict__ we) {
    __shared__ int cur[NPB];
    __shared__ float adl[NPB];
    int b = blockIdx.x;
    int nb = b * NPB;
    float C = Cptr[0];
    for (int t = threadIdx.x; t < NPB; t += 128) {
        int node = nb + t;
        cur[t] = (node < N_NODES) ? row_ptr[node] : 0;
        adl[t] = (node < N_NODES) ? ad_in[node] : 0.f;
    }
    __syncthreads();
    int n = min(bcnt[b], BCAP);
    const int* sp = stage + (size_t)b * BCAP;
    for (int i = threadIdx.x; i < n; i += 128) {
        int v = sp[i];
        int s = v & 0x1FFFF;
        int li = v >> 17;
        int pos = atomicAdd(&cur[li], 1);
        esrc[pos] = s;
        float e = as_in[s] + adl[li];
        e = fmaxf(e, NEG_SLOPE * e);   // leakyrelu
        we[pos] = __expf(e - C);
    }
}

// ---------------- both weights -> transposed bf16 [N][K] ----------------
__global__ void splitT_both_kernel(const float* __restrict__ W1, const float* __restrict__ W2,
                                   short* __restrict__ w1t, short* __restrict__ w2t) {
    int i = blockIdx.x * 256 + threadIdx.x;
    if (i < IN_C * HID_C) {
        int k = i / HID_C, n = i - k * HID_C;
        w1t[n * IN_C + k] = f2bf(W1[i]);
    } else {
        int j = i - IN_C * HID_C;
        if (j < HID_C * OUT_C) {
            int k = j / OUT_C, n = j - k * OUT_C;
            w2t[n * HID_C + k] = f2bf(W2[j]);
        }
    }
}

// ---------------- bf16 MFMA GEMM (single pass) ----------------
// C = A[M,K] @ B[K,N], Bt stored [N][K] bf16. BM=128, BN=64, 4 waves.
// OUTMODE 1: plain bf16 -> C0.  OUTMODE 2: relu(v+bias[gc]) -> bf16 C0.
template<int K, int OUTMODE>
__global__ __launch_bounds__(256)
void gemm_mfma(const short* __restrict__ Ah, const short* __restrict__ Bth,
               int N, const float* __restrict__ bias, short* __restrict__ C0) {
    __shared__ short Ah_s[128][40];
    __shared__ short Bh_s[64][40];
    int tid = threadIdx.x;
    int lane = tid & 63, wave = tid >> 6;
    int wr = wave >> 1, wc = wave & 1;
    int bm = blockIdx.y * 128, bn = blockIdx.x * 64;
    int l15 = lane & 15, kf = (lane >> 4) * 8;

    floatx4 acc[4][2];
    #pragma unroll
    for (int i = 0; i < 4; ++i)
        #pragma unroll
        for (int j = 0; j < 2; ++j) acc[i][j] = (floatx4){0.f, 0.f, 0.f, 0.f};

    int arow = tid >> 1, ac0 = (tid & 1) * 16;
    int brow = tid >> 2, bc0 = (tid & 3) * 8;
    int agm = bm + arow;
    bool aval = agm < N_NODES;

    for (int k0 = 0; k0 < K; k0 += 32) {
        short8 va0 = {0,0,0,0,0,0,0,0}, va1 = va0;
        if (aval) {
            const short* pa = Ah + (size_t)agm * K + k0 + ac0;
            va0 = *(const short8*)pa; va1 = *(const short8*)(pa + 8);
        }
        *(short8*)&Ah_s[arow][ac0]     = va0;
        *(short8*)&Ah_s[arow][ac0 + 8] = va1;
        {
            const short* pb = Bth + (size_t)(bn + brow) * K + k0 + bc0;
            *(short8*)&Bh_s[brow][bc0] = *(const short8*)pb;
        }
        __syncthreads();
        short8 afh[4], bfh[2];
        #pragma unroll
        for (int mr = 0; mr < 4; ++mr) {
            int r = wr * 64 + mr * 16 + l15;
            afh[mr] = *(const short8*)&Ah_s[r][kf];
        }
        #pragma unroll
        for (int nr = 0; nr < 2; ++nr) {
            int c = wc * 32 + nr * 16 + l15;
            bfh[nr] = *(const short8*)&Bh_s[c][kf];
        }
        #pragma unroll
        for (int mr = 0; mr < 4; ++mr)
            #pragma unroll
            for (int nr = 0; nr < 2; ++nr)
                acc[mr][nr] = __builtin_amdgcn_mfma_f32_16x16x32_bf16(afh[mr], bfh[nr], acc[mr][nr], 0, 0, 0);
        __syncthreads();
    }
    float bv[2];
    if (OUTMODE == 2) {
        #pragma unroll
        for (int nr = 0; nr < 2; ++nr) bv[nr] = bias[bn + wc * 32 + nr * 16 + l15];
    }
    #pragma unroll
    for (int mr = 0; mr < 4; ++mr) {
        #pragma unroll
        for (int reg = 0; reg < 4; ++reg) {
            int gr = bm + wr * 64 + mr * 16 + (lane >> 4) * 4 + reg;
            if (gr < N_NODES) {
                #pragma unroll
                for (int nr = 0; nr < 2; ++nr) {
                    int gc = bn + wc * 32 + nr * 16 + l15;
                    float v = acc[mr][nr][reg];
                    if (OUTMODE == 2) v = fmaxf(v + bv[nr], 0.f);
                    C0[(size_t)gr * N + gc] = f2bf(v);
                }
            }
        }
    }
}

// ---------------- alpha2 from h2 (bf16) ----------------
__global__ __launch_bounds__(256)
void alpha_bf16_128(const short* __restrict__ h, const float* __restrict__ a_src,
                    const float* __restrict__ a_dst, float* __restrict__ as_out,
                    float* __restrict__ ad_out) {
    int gt = blockIdx.x * blockDim.x + threadIdx.x;
    int node = gt >> 6, lane = gt & 63;
    if (node >= N_NODES) return;
    unsigned u = *(const unsigned*)&h[(size_t)node * OUT_C + lane * 2];
    float v0 = bf2f((short)(u & 0xFFFFu));
    float v1 = bf2f((short)(u >> 16));
    floatx2 as2 = *(const floatx2*)&a_src[lane * 2];
    floatx2 ad2 = *(const floatx2*)&a_dst[lane * 2];
    float s = v0 * as2[0] + v1 * as2[1];
    float d = v0 * ad2[0] + v1 * ad2[1];
    #pragma unroll
    for (int off = 32; off; off >>= 1) {
        s += __shfl_down(s, off);
        d += __shfl_down(d, off);
    }
    if (lane == 0) { as_out[node] = s; ad_out[node] = d; }
}

// ---------------- layer-1 aggregate: single pass, precomputed we, bf16 u out ----------------
__global__ __launch_bounds__(256)
void aggregate1_kernel(const short* __restrict__ h, const float* __restrict__ we,
                       const int* __restrict__ row_ptr, const int* __restrict__ esrc,
                       short* __restrict__ o_u) {
    int gt = blockIdx.x * blockDim.x + threadIdx.x;
    int node = gt >> 6, lane = gt & 63;
    if (node >= N_NODES) return;
    int beg = row_ptr[node], end = row_ptr[node + 1];
    int grp = lane >> 4, l = lane & 15;
    float acc[8] = {};
    float zl = 0.f;
    int i = beg;
    for (; i + 16 <= end; i += 16) {
        int e0 = i + grp, e1 = e0 + 4, e2 = e0 + 8, e3 = e0 + 12;
        int s0 = esrc[e0], s1 = esrc[e1], s2 = esrc[e2], s3 = esrc[e3];
        float w0 = we[e0], w1 = we[e1], w2 = we[e2], w3 = we[e3];
        short8 hv0 = *(const short8*)&h[(size_t)s0 * 128 + l * 8];
        short8 hv1 = *(const short8*)&h[(size_t)s1 * 128 + l * 8];
        short8 hv2 = *(const short8*)&h[(size_t)s2 * 128 + l * 8];
        short8 hv3 = *(const short8*)&h[(size_t)s3 * 128 + l * 8];
        zl += (w0 + w1) + (w2 + w3);
        #pragma unroll
        for (int j = 0; j < 8; ++j) acc[j] += w0 * bf2f(hv0[j]);
        #pragma unroll
        for (int j = 0; j < 8; ++j) acc[j] += w1 * bf2f(hv1[j]);
        #pragma unroll
        for (int j = 0; j < 8; ++j) acc[j] += w2 * bf2f(hv2[j]);
        #pragma unroll
        for (int j = 0; j < 8; ++j) acc[j] += w3 * bf2f(hv3[j]);
    }
    for (; i < end; i += 4) {
        int e = i + grp;
        bool v = e < end;
        int s = esrc[v ? e : beg];
        float w = v ? we[e] : 0.f;
        short8 hv = *(const short8*)&h[(size_t)s * 128 + l * 8];
        zl += w;
        #pragma unroll
        for (int j = 0; j < 8; ++j) acc[j] += w * bf2f(hv[j]);
    }
    zl += __shfl_xor(zl, 16);
    zl += __shfl_xor(zl, 32);
    #pragma unroll
    for (int j = 0; j < 8; ++j) {
        acc[j] += __shfl_xor(acc[j], 16);
        acc[j] += __shfl_xor(acc[j], 32);
    }
    float invz = 1.f / zl;
    if (lane < 16) {
        short8 oh;
        #pragma unroll
        for (int j = 0; j < 8; ++j) oh[j] = f2bf(acc[j] * invz);
        *(short8*)&o_u[(size_t)node * 128 + l * 8] = oh;
    }
}

// ---------------- layer-2 aggregate: single pass, inline we from as2/ad2, fp32 out ----------------
__global__ __launch_bounds__(256)
void aggregate2_kernel(const short* __restrict__ h, const float* __restrict__ as2,
                       const float* __restrict__ ad2, const float* __restrict__ Cptr,
                       const int* __restrict__ row_ptr, const int* __restrict__ esrc,
                       const float* __restrict__ bias, float* __restrict__ out) {
    int gt = blockIdx.x * blockDim.x + threadIdx.x;
    int node = gt >> 6, lane = gt & 63;
    if (node >= N_NODES) return;
    int beg = row_ptr[node], end = row_ptr[node + 1];
    float C = Cptr[0];
    float adn = ad2[node];
    int grp = lane >> 4, l = lane & 15;
    float acc[8] = {};
    float zl = 0.f;
    int i = beg;
    for (; i + 16 <= end; i += 16) {
        int e0 = i + grp, e1 = e0 + 4, e2 = e0 + 8, e3 = e0 + 12;
        int s0 = esrc[e0], s1 = esrc[e1], s2 = esrc[e2], s3 = esrc[e3];
        float t0 = as2[s0] + adn, t1 = as2[s1] + adn, t2 = as2[s2] + adn, t3 = as2[s3] + adn;
        t0 = fmaxf(t0, NEG_SLOPE * t0); t1 = fmaxf(t1, NEG_SLOPE * t1);
        t2 = fmaxf(t2, NEG_SLOPE * t2); t3 = fmaxf(t3, NEG_SLOPE * t3);
        float w0 = __expf(t0 - C), w1 = __expf(t1 - C);
        float w2 = __expf(t2 - C), w3 = __expf(t3 - C);
        short8 hv0 = *(const short8*)&h[(size_t)s0 * 128 + l * 8];
        short8 hv1 = *(const short8*)&h[(size_t)s1 * 128 + l * 8];
        short8 hv2 = *(const short8*)&h[(size_t)s2 * 128 + l * 8];
        short8 hv3 = *(const short8*)&h[(size_t)s3 * 128 + l * 8];
        zl += (w0 + w1) + (w2 + w3);
        #pragma unroll
        for (int j = 0; j < 8; ++j) acc[j] += w0 * bf2f(hv0[j]);
        #pragma unroll
        for (int j = 0; j < 8; ++j) acc[j] += w1 * bf2f(hv1[j]);
        #pragma unroll
        for (int j = 0; j < 8; ++j) acc[j] += w2 * bf2f(hv2[j]);
        #pragma unroll
        for (int j = 0; j < 8; ++j) acc[j] += w3 * bf2f(hv3[j]);
    }
    for (; i < end; i += 4) {
        int e = i + grp;
        bool v = e < end;
        int s = esrc[v ? e : beg];
        float t = as2[s] + adn;
        t = fmaxf(t, NEG_SLOPE * t);
        float w = v ? __expf(t - C) : 0.f;
        short8 hv = *(const short8*)&h[(size_t)s * 128 + l * 8];
        zl += w;
        #pragma unroll
        for (int j = 0; j < 8; ++j) acc[j] += w * bf2f(hv[j]);
    }
    zl += __shfl_xor(zl, 16);
    zl += __shfl_xor(zl, 32);
    #pragma unroll
    for (int j = 0; j < 8; ++j) {
        acc[j] += __shfl_xor(acc[j], 16);
        acc[j] += __shfl_xor(acc[j], 32);
    }
    float invz = 1.f / zl;
    if (lane < 16) {
        const float* brow = &bias[l * 8];
        floatx4 o0, o1;
        #pragma unroll
        for (int j = 0; j < 4; ++j) {
            o0[j] = acc[j] * invz + brow[j];
            o1[j] = acc[j + 4] * invz + brow[j + 4];
        }
        float* orow = &out[(size_t)node * 128 + l * 8];
        *(floatx4*)orow = o0;
        *(floatx4*)(orow + 4) = o1;
    }
}

// ---------------- launch ----------------
extern "C" void kernel_launch(void* const* d_in, const int* in_sizes, int n_in,
                              void* d_out, int out_size, void* d_ws, size_t ws_size,
                              hipStream_t stream) {
    const float* x   = (const float*)d_in[0];
    const int*   ei  = (const int*)d_in[1];
    const float* W1  = (const float*)d_in[2];
    const float* a1s = (const float*)d_in[3];
    const float* a1d = (const float*)d_in[4];
    const float* b1  = (const float*)d_in[5];
    const float* W2  = (const float*)d_in[6];
    const float* a2s = (const float*)d_in[7];
    const float* a2d = (const float*)d_in[8];
    const float* b2  = (const float*)d_in[9];
    float* out = (float*)d_out;

    const int* e_src = ei;
    const int* e_dst = ei + N_EDGESX;

    char* ws = (char*)d_ws;
    const size_t OFF_XB    = 0;             // bf16 [N][128]
    const size_t OFF_UH    = 12800000;      // bf16 [N][128]
    const size_t OFF_G1H   = 25600000;      // bf16 [N][256]
    const size_t OFF_H2    = 51200000;      // bf16 [N][128]
    const size_t OFF_W1T   = 64000000;      // bf16 [256][128]
    const size_t OFF_W2T   = 64065536;      // bf16 [128][256]
    const size_t OFF_P1S   = 64131072;
    const size_t OFF_P1D   = 64131584;
    const size_t OFF_CMAX  = 64132096;      // 2 floats
    const size_t OFF_AS    = 64132352;
    const size_t OFF_AD    = 64332544;
    const size_t OFF_RP    = 64532736;
    const size_t OFF_BSUM  = 64733184;      // NBUCK ints
    const size_t OFF_BCNT  = 64735232;      // NBUCK ints
    const size_t OFF_ESRC  = 64737280;      // E_TOT*4
    const size_t OFF_WE    = 68137280;      // E_TOT*4
    const size_t OFF_STAGE = 71537280;      // int [NBUCK][BCAP] = 5.12 MB

    short* xb   = (short*)(ws + OFF_XB);
    short* uh   = (short*)(ws + OFF_UH);
    short* g1h  = (short*)(ws + OFF_G1H);
    short* h2   = (short*)(ws + OFF_H2);
    short* w1t  = (short*)(ws + OFF_W1T);
    short* w2t  = (short*)(ws + OFF_W2T);
    float* p1s  = (float*)(ws + OFF_P1S);
    float* p1d  = (float*)(ws + OFF_P1D);
    float* cmax = (float*)(ws + OFF_CMAX);
    float* as_b = (float*)(ws + OFF_AS);
    float* ad_b = (float*)(ws + OFF_AD);
    int* row_ptr = (int*)(ws + OFF_RP);
    int* bsum    = (int*)(ws + OFF_BSUM);
    int* bcnt    = (int*)(ws + OFF_BCNT);
    int* esrc    = (int*)(ws + OFF_ESRC);
    float* web   = (float*)(ws + OFF_WE);
    int* stage   = (int*)(ws + OFF_STAGE);

    int ngrid = (N_NODES * 64 + 255) / 256;

    // --- alpha1 (from x) + xb split + global offset C1 ---
    gemv_p_kernel<IN_C, HID_C><<<1, 256, 0, stream>>>(W1, a1s, a1d, p1s, p1d);
    alpha_x_kernel<<<ngrid, 256, 0, stream>>>(x, p1s, p1d, as_b, ad_b, xb);
    maxred_kernel<<<1, 1024, 0, stream>>>(as_b, ad_b, cmax);

    // --- bucketed CSR build (+ fused layer-1 weights) ---
    hipMemsetAsync(bcnt, 0, NBUCK * sizeof(int), stream);
    binA_kernel<<<NABLK, 256, 0, stream>>>(e_src, e_dst, bcnt, stage);
    bucket_count_scan_kernel<<<NBUCK, 128, 0, stream>>>(bcnt, stage, row_ptr, bsum);
    scan_bucket_kernel<<<1, 512, 0, stream>>>(bsum, row_ptr);
    scan_add_kernel<<<(N_NODES + 255) / 256, 256, 0, stream>>>(row_ptr, bsum);
    bucket_scatter_kernel<<<NBUCK, 128, 0, stream>>>(bcnt, stage, row_ptr, as_b, ad_b, cmax, esrc, web);

    // --- weight transpose+cast (both) ---
    splitT_both_kernel<<<(IN_C * HID_C + HID_C * OUT_C + 255) / 256, 256, 0, stream>>>(W1, W2, w1t, w2t);

    // --- layer 1: aggregate x (single pass), then transform (bias+relu fused) ---
    aggregate1_kernel<<<ngrid, 256, 0, stream>>>(xb, web, row_ptr, esrc, uh);
    gemm_mfma<IN_C, 2><<<dim3(HID_C / 64, (N_NODES + 127) / 128), 256, 0, stream>>>(
        uh, w1t, HID_C, b1, g1h);

    // --- layer 2: transform, then aggregate (inline weights) ---
    gemm_mfma<HID_C, 1><<<dim3(OUT_C / 64, (N_NODES + 127) / 128), 256, 0, stream>>>(
        g1h, w2t, OUT_C, nullptr, h2);
    alpha_bf16_128<<<ngrid, 256, 0, stream>>>(h2, a2s, a2d, as_b, ad_b);
    maxred_kernel<<<1, 1024, 0, stream>>>(as_b, ad_b, cmax + 1);
    aggregate2_kernel<<<ngrid, 256, 0, stream>>>(h2, as_b, ad_b, cmax + 1, row_ptr, esrc, b2, out);
}